// Round 3
// baseline (547.586 us; speedup 1.0000x reference)
//
#include <hip/hip_runtime.h>
#include <stdint.h>

#define BB 16
#define HH 1024
#define II 512

// ---- output element offsets (f32 elements, concat in return order) ----
#define OFF_H    0L
#define OFF_C    16384L
#define OFF_EWIX 32768L
#define OFF_EWIH 8421376L
#define OFF_EBI  25198592L
#define OFF_EWFX 25214976L
#define OFF_EWFH 33603584L
#define OFF_EBF  50380800L
#define OFF_EWCX 50397184L
#define OFF_EWCH 58785792L
#define OFF_EBC  75563008L

__device__ __forceinline__ void load8f(const float* __restrict__ p, float* o) {
    float4 a = *(const float4*)p;
    float4 b = *(const float4*)(p + 4);
    o[0] = a.x; o[1] = a.y; o[2] = a.z; o[3] = a.w;
    o[4] = b.x; o[5] = b.y; o[6] = b.z; o[7] = b.w;
}

// ---------------------------------------------------------------------------
// Kernel 1: gate preactivations (4 skinny GEMVs) + pointwise LSTM cell +
// e_b updates + stash per-(b,h) coefficients {f, a_i, a_f, a_c} in ws (f32).
// One wave (64 lanes) per h-row; lanes span the K dimension (8 f32/lane).
// ---------------------------------------------------------------------------
__global__ __launch_bounds__(64) void k_gates(
    const float* __restrict__ x,
    const float* __restrict__ w_ix, const float* __restrict__ w_ih, const float* __restrict__ b_i,
    const float* __restrict__ w_fx, const float* __restrict__ w_fh, const float* __restrict__ b_f,
    const float* __restrict__ w_ox, const float* __restrict__ w_oh, const float* __restrict__ b_o,
    const float* __restrict__ w_cx, const float* __restrict__ w_ch, const float* __restrict__ b_c,
    const float* __restrict__ h_last, const float* __restrict__ c_last,
    const float* __restrict__ e_b_i, const float* __restrict__ e_b_f, const float* __restrict__ e_b_c,
    float* __restrict__ out, float* __restrict__ ws)
{
    const int h = blockIdx.x;
    const int lane = threadIdx.x;

    float acc0[BB], acc1[BB], acc2[BB], acc3[BB];
    #pragma unroll
    for (int b = 0; b < BB; b++) { acc0[b] = 0.f; acc1[b] = 0.f; acc2[b] = 0.f; acc3[b] = 0.f; }

    // --- x segment: K = 512 = 64 lanes * 8 ---
    {
        const int k = lane * 8;
        float wi[8], wf[8], wo[8], wc[8];
        load8f(w_ix + (size_t)h * II + k, wi);
        load8f(w_fx + (size_t)h * II + k, wf);
        load8f(w_ox + (size_t)h * II + k, wo);
        load8f(w_cx + (size_t)h * II + k, wc);
        #pragma unroll
        for (int b = 0; b < BB; b++) {
            float xv[8];
            load8f(x + b * II + k, xv);
            #pragma unroll
            for (int e = 0; e < 8; e++) {
                acc0[b] += wi[e] * xv[e];
                acc1[b] += wf[e] * xv[e];
                acc2[b] += wo[e] * xv[e];
                acc3[b] += wc[e] * xv[e];
            }
        }
    }
    // --- h segments: K = 1024 = 2 chunks of 512 ---
    #pragma unroll
    for (int c0 = 0; c0 < 2; c0++) {
        const int k = c0 * 512 + lane * 8;
        float wi[8], wf[8], wo[8], wc[8];
        load8f(w_ih + (size_t)h * HH + k, wi);
        load8f(w_fh + (size_t)h * HH + k, wf);
        load8f(w_oh + (size_t)h * HH + k, wo);
        load8f(w_ch + (size_t)h * HH + k, wc);
        #pragma unroll
        for (int b = 0; b < BB; b++) {
            float hv[8];
            load8f(h_last + b * HH + k, hv);
            #pragma unroll
            for (int e = 0; e < 8; e++) {
                acc0[b] += wi[e] * hv[e];
                acc1[b] += wf[e] * hv[e];
                acc2[b] += wo[e] * hv[e];
                acc3[b] += wc[e] * hv[e];
            }
        }
    }

    // --- cross-lane reduction: LDS transpose (64 values x 64 lanes) ---
    __shared__ float red[64][65];
    #pragma unroll
    for (int b = 0; b < BB; b++) {
        red[lane][b]      = acc0[b];
        red[lane][16 + b] = acc1[b];
        red[lane][32 + b] = acc2[b];
        red[lane][48 + b] = acc3[b];
    }
    __syncthreads();
    float pre = 0.f;
    #pragma unroll
    for (int l = 0; l < 64; l++) pre += red[l][lane];
    // lane j now holds preactivation of gate (j>>4), batch (j&15), row h.

    const int bb = lane & 15;
    const float pi0 = __shfl(pre, bb,      64);
    const float pf0 = __shfl(pre, bb + 16, 64);
    const float po0 = __shfl(pre, bb + 32, 64);
    const float pc0 = __shfl(pre, bb + 48, 64);

    if (lane < BB) {
        const int b = lane;
        const int idx = b * HH + h;
        const float pi = pi0 + b_i[h];
        const float pf = pf0 + b_f[h];
        const float po = po0 + b_o[h];
        const float pc = pc0 + b_c[h];
        const float ig = 1.f / (1.f + __expf(-pi));
        const float fg = 1.f / (1.f + __expf(-pf));
        const float og = 1.f / (1.f + __expf(-po));
        const float chat = tanhf(pc);
        const float cl = c_last[idx];
        const float cnew = fg * cl + ig * chat;
        const float hnew = og * cnew;
        const float di = ig * (1.f - ig);
        const float df = fg * (1.f - fg);
        const float dch = 1.f - chat * chat;
        const float ai = di * chat;
        const float af = df * cl;
        const float ac = dch * ig;

        out[OFF_H   + idx] = hnew;
        out[OFF_C   + idx] = cnew;
        out[OFF_EBI + idx] = e_b_i[idx] * fg + ai;
        out[OFF_EBF + idx] = e_b_f[idx] * fg + af;
        out[OFF_EBC + idx] = e_b_c[idx] * fg + ac;

        ws[idx]          = fg;
        ws[16384 + idx]  = ai;
        ws[32768 + idx]  = af;
        ws[49152 + idx]  = ac;
    }
}

// ---------------------------------------------------------------------------
// Kernel 2: the six big eligibility-trace updates (pure elementwise, HBM-bound)
//   new_e[b,h,j] = e[b,h,j]*f[b,h] + a[b,h]*src[b,j]
// blockIdx.y = tensor t in {ix, ih, fx, fh, cx, ch}; 8 f32 per thread (32 B).
// ---------------------------------------------------------------------------
__global__ __launch_bounds__(256) void k_trace(
    const float* __restrict__ x, const float* __restrict__ h_last,
    const float* __restrict__ e_ix, const float* __restrict__ e_ih,
    const float* __restrict__ e_fx, const float* __restrict__ e_fh,
    const float* __restrict__ e_cx, const float* __restrict__ e_ch,
    const float* __restrict__ ws, float* __restrict__ out)
{
    const int t = blockIdx.y;              // 0..5
    const int is_h = t & 1;
    const int shift = 9 + is_h;            // log2(rowlen): 512 or 1024
    const long n_thr = (long)(BB * HH) << (shift - 3);
    const long gid = (long)blockIdx.x * 256 + threadIdx.x;
    if (gid >= n_thr) return;
    const long elem0 = gid * 8;
    const int row = (int)(elem0 >> shift);           // b*H + h
    const int j0  = (int)(elem0 & ((1 << shift) - 1));
    const int b   = row >> 10;

    const float* e_in;
    long ooff;
    switch (t) {
        case 0:  e_in = e_ix; ooff = OFF_EWIX; break;
        case 1:  e_in = e_ih; ooff = OFF_EWIH; break;
        case 2:  e_in = e_fx; ooff = OFF_EWFX; break;
        case 3:  e_in = e_fh; ooff = OFF_EWFH; break;
        case 4:  e_in = e_cx; ooff = OFF_EWCX; break;
        default: e_in = e_ch; ooff = OFF_EWCH; break;
    }
    const float* src = is_h ? h_last : x;
    const int a_sel = t >> 1;                        // 0:a_i 1:a_f 2:a_c
    const float fl = ws[row];
    const float aa = ws[(a_sel + 1) * 16384 + row];

    float ev[8], sv[8], r[8];
    load8f(e_in + elem0, ev);
    load8f(src + ((long)b << shift) + j0, sv);
    #pragma unroll
    for (int e = 0; e < 8; e++) r[e] = ev[e] * fl + aa * sv[e];

    float4 o0, o1;
    o0.x = r[0]; o0.y = r[1]; o0.z = r[2]; o0.w = r[3];
    o1.x = r[4]; o1.y = r[5]; o1.z = r[6]; o1.w = r[7];
    *(float4*)(out + ooff + elem0)     = o0;
    *(float4*)(out + ooff + elem0 + 4) = o1;
}

extern "C" void kernel_launch(void* const* d_in, const int* in_sizes, int n_in,
                              void* d_out, int out_size, void* d_ws, size_t ws_size,
                              hipStream_t stream) {
    const float* x      = (const float*)d_in[0];
    const float* w_ix   = (const float*)d_in[1];
    const float* w_ih   = (const float*)d_in[2];
    const float* b_i    = (const float*)d_in[3];
    const float* w_fx   = (const float*)d_in[4];
    const float* w_fh   = (const float*)d_in[5];
    const float* b_f    = (const float*)d_in[6];
    const float* w_ox   = (const float*)d_in[7];
    const float* w_oh   = (const float*)d_in[8];
    const float* b_o    = (const float*)d_in[9];
    const float* w_cx   = (const float*)d_in[10];
    const float* w_ch   = (const float*)d_in[11];
    const float* b_c    = (const float*)d_in[12];
    const float* h_last = (const float*)d_in[13];
    const float* c_last = (const float*)d_in[14];
    const float* e_ix   = (const float*)d_in[15];
    const float* e_ih   = (const float*)d_in[16];
    const float* e_b_i  = (const float*)d_in[17];
    const float* e_fx   = (const float*)d_in[18];
    const float* e_fh   = (const float*)d_in[19];
    const float* e_b_f  = (const float*)d_in[20];
    const float* e_cx   = (const float*)d_in[21];
    const float* e_ch   = (const float*)d_in[22];
    const float* e_b_c  = (const float*)d_in[23];
    float* out = (float*)d_out;
    float* ws  = (float*)d_ws;

    k_gates<<<dim3(HH), dim3(64), 0, stream>>>(
        x, w_ix, w_ih, b_i, w_fx, w_fh, b_f, w_ox, w_oh, b_o, w_cx, w_ch, b_c,
        h_last, c_last, e_b_i, e_b_f, e_b_c, out, ws);

    k_trace<<<dim3(8192, 6), dim3(256), 0, stream>>>(
        x, h_last, e_ix, e_ih, e_fx, e_fh, e_cx, e_ch, ws, out);
}